// Round 13
// baseline (160.693 us; speedup 1.0000x reference)
//
#include <hip/hip_runtime.h>

#define NROWS 65536
#define DIM 64
#define KCODES 8192
#define DECAYF 0.99f
#define EPSV 1e-5f
#define KD (KCODES * DIM)
#define KSPLIT 4
#define KC (KCODES / KSPLIT)   // 2048 codes per split chunk
#define ROUNDS (KC / 128)      // 16 rounds x 128 codes (16 KB) per chunk

typedef _Float16 half8 __attribute__((ext_vector_type(8)));
typedef float f32x16 __attribute__((ext_vector_type(16)));

// ws layout (float offsets) — total ~4.0 MB
#define WS_STATS  0          // 256: mean[64], rstd[64], running_std[64]
#define WS_NHCKP  256        // 8192: 10.6875 - ||e||^2/2, PERMUTED to C-layout
#define WS_EBUF   8448       // 262144: 8192 codes x 64 dims f16 (1 MB)
#define WS_PSUM   270592     // 65536 (1024 blocks x 64)
#define WS_PSQ    336128     // 65536
#define WS_PACKED 401664     // 65536 u32
#define WS_DW     467200     // 524288
#define WS_COUNTS 991488     // 8192
// PACKED..COUNTS contiguous (598016 floats) zeroed by k_prep_stats
#define ZERO_F4   149504

// ---------------- K1: fused prep(emb) + colstats partial(x) + ws zeroing ---
// grid 1024 x 256 threads.
// ebuf layout (half8): idx = R*1024 + t*256 + c*64 + h*32 + col
//   code = R*128 + t*32 + col ; dims = c*16 + h*8 + j   (unchanged r8 layout)
// nhckP: permuted so k_argmin can load 16 consecutive floats as the MFMA
//   C-init: nhckP[T*32 + h*16 + reg] = nv(code T*32 + crow(reg,h)),
//   crow(reg,h) = (reg&3) + 8*(reg>>2) + 4*h  (m74/m101 32x32 C layout).
__global__ __launch_bounds__(256) void k_prep_stats(
    const float* __restrict__ emb, const float* __restrict__ x,
    half8* __restrict__ ebuf, float* __restrict__ nhckP,
    float* __restrict__ psum, float* __restrict__ psq,
    float4* __restrict__ zbase)
{
    const int tid = blockIdx.x * 256 + threadIdx.x;

    // ---- part C: zero packed+dw+counts ----
    if (tid < ZERO_F4) zbase[tid] = float4{0.f, 0.f, 0.f, 0.f};

    // ---- part A: emb -> f16 centered plane + permuted nhck ----
    if (tid < 65536) {
        const int code = tid >> 3, sub = tid & 7;
        const int c = sub >> 1, h = sub & 1;
        const float* e = emb + (size_t)code * DIM + c * 16 + h * 8;
        float4 a = *(const float4*)e;
        float4 b = *(const float4*)(e + 4);
        float f[8] = {a.x, a.y, a.z, a.w, b.x, b.y, b.z, b.w};
        half8 hh;
        float ssq = 0.f;
        #pragma unroll
        for (int i = 0; i < 8; ++i) {
            hh[i] = (_Float16)(f[i] - 0.5f);   // centered: halves f16 quant err
            ssq += f[i] * f[i];
        }
        #pragma unroll
        for (int o = 1; o < 8; o <<= 1) ssq += __shfl_xor(ssq, o, 64);
        if (sub == 0) {
            const int c32 = code & 31;
            const int hh2 = (c32 >> 2) & 1;
            const int rem = c32 - 4 * hh2;
            const int reg = (rem & 3) + 4 * (rem >> 3);
            nhckP[(code >> 5) * 32 + hh2 * 16 + reg] = 10.6875f - 0.5f * ssq;
        }
        const int R = code >> 7, t = (code >> 5) & 3, col = code & 31;
        ebuf[(size_t)R * 1024 + t * 256 + c * 64 + h * 32 + col] = hh;
    }

    // ---- part B: column partial sums over 64 rows ----
    {
        const int wave = threadIdx.x >> 6;
        const int col  = threadIdx.x & 63;
        const int base = blockIdx.x * 64;
        float s = 0.f, q = 0.f;
        #pragma unroll 4
        for (int i = 0; i < 16; ++i) {
            int r = base + i * 4 + wave;
            float v = x[(size_t)r * DIM + col];
            s += v;
            q += v * v;
        }
        __shared__ float ls[4][64];
        __shared__ float lq[4][64];
        ls[wave][col] = s;
        lq[wave][col] = q;
        __syncthreads();
        if (threadIdx.x < 64) {
            psum[blockIdx.x * 64 + col] = ls[0][col] + ls[1][col] + ls[2][col] + ls[3][col];
            psq[blockIdx.x * 64 + col]  = lq[0][col] + lq[1][col] + lq[2][col] + lq[3][col];
        }
    }
}

// ---------------- K1b: finalize stats (256 thr, 4-way split) ---------------
__global__ __launch_bounds__(256) void k_colstats_final(
    const float* __restrict__ psum, const float* __restrict__ psq,
    float* __restrict__ stats)
{
    const int col = threadIdx.x & 63, part = threadIdx.x >> 6;
    float s = 0.f, q = 0.f;
    for (int i = part * 256; i < part * 256 + 256; ++i) {
        s += psum[i * 64 + col];
        q += psq[i * 64 + col];
    }
    __shared__ float ls[4][64];
    __shared__ float lq[4][64];
    ls[part][col] = s;
    lq[part][col] = q;
    __syncthreads();
    if (threadIdx.x < 64) {
        s = ls[0][col] + ls[1][col] + ls[2][col] + ls[3][col];
        q = lq[0][col] + lq[1][col] + lq[2][col] + lq[3][col];
        const float n = (float)NROWS;
        float mean = s / n;
        float var = q / n - mean * mean;
        if (var < 0.f) var = 0.f;
        stats[col]       = mean;
        stats[64 + col]  = 1.0f / sqrtf(var + EPSV);
        stats[128 + col] = sqrtf(var * (n / (n - 1.0f)) + EPSV);
    }
}

// ---------------- K3: swapped-operand 32x32 MFMA argmin --------------------
// acc = mfma(A=codes(LDS), B=rows(regs), C=nhckP-vector): C[code][row] —
// lane holds 16 codes of ONE row (col=lane&31=row, code=crow(reg,lane>>5)).
// Select = in-lane tree over the 16 regs: bfi 4-bit inline key (15-i, crow
// monotone in i -> smaller code wins ties), 15-max tree, then rebuild the
// full 13-bit key (8191-code) for cross-tile/cross-chunk ordering.
// State: best = 1 float per row-tile (vs 16) — keeps matrix state in arch
// VGPRs, no AGPR read/write round-trips on the select path (r12's 2.7x
// VALU excess theory).
__device__ __forceinline__ void gload16(const void* g, void* l)
{
    __builtin_amdgcn_global_load_lds(
        (const __attribute__((address_space(1))) void*)g,
        (__attribute__((address_space(3))) void*)l, 16, 0, 0);
}

__device__ __forceinline__ void build_rowfrag(const float* __restrict__ xr,
                                              const float* __restrict__ stats,
                                              int h, half8* a)
{
    #pragma unroll
    for (int c = 0; c < 4; ++c) {
        const int d = c * 16 + h * 8;
        float4 v0 = *(const float4*)(xr + d);
        float4 v1 = *(const float4*)(xr + d + 4);
        float4 m0 = *(const float4*)(stats + d);
        float4 m1 = *(const float4*)(stats + d + 4);
        float4 s0 = *(const float4*)(stats + 64 + d);
        float4 s1 = *(const float4*)(stats + 64 + d + 4);
        a[c][0] = (_Float16)((v0.x - m0.x) * s0.x);
        a[c][1] = (_Float16)((v0.y - m0.y) * s0.y);
        a[c][2] = (_Float16)((v0.z - m0.z) * s0.z);
        a[c][3] = (_Float16)((v0.w - m0.w) * s0.w);
        a[c][4] = (_Float16)((v1.x - m1.x) * s1.x);
        a[c][5] = (_Float16)((v1.y - m1.y) * s1.y);
        a[c][6] = (_Float16)((v1.z - m1.z) * s1.z);
        a[c][7] = (_Float16)((v1.w - m1.w) * s1.w);
    }
}

// tree-select: returns max(best, packed winner of this tile)
__device__ __forceinline__ float tile_select(f32x16 acc, unsigned ktile, float best)
{
    float u[16];
    #pragma unroll
    for (int i = 0; i < 16; ++i)
        u[i] = __uint_as_float((__float_as_uint(acc[i]) & 0xFFFFFFF0u)
                               | (unsigned)(15 - i));
    #pragma unroll
    for (int s = 8; s >= 1; s >>= 1) {
        #pragma unroll
        for (int i = 0; i < s; ++i) u[i] = fmaxf(u[i], u[i + s]);
    }
    unsigned mb = __float_as_uint(u[0]);
    unsigned i2 = 15u - (mb & 15u);
    unsigned crow = (i2 & 3u) + ((i2 >> 2) << 3);       // + 4h folded in ktile
    unsigned uf = (mb & 0xFFFFE000u) | (ktile - crow);  // key = 8191-code
    return fmaxf(best, __uint_as_float(uf));
}

__global__ __launch_bounds__(256) void k_argmin32(
    const float* __restrict__ x, const half8* __restrict__ ebuf,
    const float* __restrict__ nhckP, const float* __restrict__ stats,
    unsigned* __restrict__ packed)
{
    __shared__ half8 smem[2048];   // 32 KB: 2 x 16 KB rounds

    const int lane = threadIdx.x & 63;
    const int wave = threadIdx.x >> 6;
    const int kc = blockIdx.y;
    const int col = lane & 31, h = lane >> 5;
    const int rowbase = blockIdx.x * 256 + wave * 64;

    // ---- row fragments (B operand) for the two row-tiles ----
    half8 b0[4], b1[4];
    build_rowfrag(x + (size_t)(rowbase + col) * DIM, stats, h, b0);
    build_rowfrag(x + (size_t)(rowbase + 32 + col) * DIM, stats, h, b1);

    float best0 = -3.4e38f, best1 = -3.4e38f;

    const half8* esrc = ebuf + (size_t)kc * (KC * 8);   // 8 half8 per code
    const float* nvp = nhckP + kc * KC + h * 16;
    const unsigned kbase = (unsigned)(8191 - kc * KC - 4 * h);

    // prologue stage (256 thr x 16 B x 4 = 16 KB)
    {
        const char* src = (const char*)esrc + threadIdx.x * 16;
        char* dst = (char*)smem + threadIdx.x * 16;
        #pragma unroll
        for (int i = 0; i < 4; ++i) gload16(src + i * 4096, dst + i * 4096);
    }
    __syncthreads();

    for (int R = 0; R < ROUNDS; ++R) {
        const int buf = R & 1;
        if (R < ROUNDS - 1) {
            const char* src = (const char*)esrc + (size_t)(R + 1) * 16384 + threadIdx.x * 16;
            char* dst = (char*)smem + (buf ^ 1) * 16384 + threadIdx.x * 16;
            #pragma unroll
            for (int i = 0; i < 4; ++i) gload16(src + i * 4096, dst + i * 4096);
        }

        const half8* sb = smem + buf * 1024 + lane;
        #pragma unroll
        for (int t = 0; t < 4; ++t) {
            half8 a0 = sb[t * 256];
            half8 a1 = sb[t * 256 + 64];
            half8 a2 = sb[t * 256 + 128];
            half8 a3 = sb[t * 256 + 192];
            // C-init: 16 consecutive nhckP floats (64 B, aligned)
            f32x16 ci = *(const f32x16*)(nvp + R * 128 + t * 32);
            f32x16 acc0, acc1;
            __builtin_amdgcn_s_setprio(1);
            acc0 = __builtin_amdgcn_mfma_f32_32x32x16_f16(a0, b0[0], ci, 0, 0, 0);
            acc1 = __builtin_amdgcn_mfma_f32_32x32x16_f16(a0, b1[0], ci, 0, 0, 0);
            acc0 = __builtin_amdgcn_mfma_f32_32x32x16_f16(a1, b0[1], acc0, 0, 0, 0);
            acc1 = __builtin_amdgcn_mfma_f32_32x32x16_f16(a1, b1[1], acc1, 0, 0, 0);
            acc0 = __builtin_amdgcn_mfma_f32_32x32x16_f16(a2, b0[2], acc0, 0, 0, 0);
            acc1 = __builtin_amdgcn_mfma_f32_32x32x16_f16(a2, b1[2], acc1, 0, 0, 0);
            acc0 = __builtin_amdgcn_mfma_f32_32x32x16_f16(a3, b0[3], acc0, 0, 0, 0);
            acc1 = __builtin_amdgcn_mfma_f32_32x32x16_f16(a3, b1[3], acc1, 0, 0, 0);
            __builtin_amdgcn_s_setprio(0);
            const unsigned ktile = kbase - (unsigned)(R * 128 + t * 32);
            best0 = tile_select(acc0, ktile, best0);
            best1 = tile_select(acc1, ktile, best1);
        }
        __syncthreads();
    }

    // merge the two h-halves (lane l <-> l+32 hold same row, disjoint codes)
    best0 = fmaxf(best0, __shfl_xor(best0, 32, 64));
    best1 = fmaxf(best1, __shfl_xor(best1, 32, 64));
    if (h == 0) {
        unsigned u0 = __float_as_uint(best0);
        u0 = (u0 & 0x80000000u) ? ~u0 : (u0 | 0x80000000u);
        atomicMax(&packed[rowbase + col], u0);
        unsigned u1 = __float_as_uint(best1);
        u1 = (u1 & 0x80000000u) ? ~u1 : (u1 | 0x80000000u);
        atomicMax(&packed[rowbase + 32 + col], u1);
    }
}

// ---------------- K4: scatter (segment sums) + counts ----------------
__global__ __launch_bounds__(256) void k_scatter(
    const float* __restrict__ x, const float* __restrict__ stats,
    const unsigned* __restrict__ packed,
    float* __restrict__ dw, float* __restrict__ counts)
{
    const int t = blockIdx.x * 256 + threadIdx.x;
    const int row = t >> 6, col = t & 63;
    const unsigned v = packed[row];
    const unsigned key = (v & 0x80000000u) ? (v & 8191u) : (~v & 8191u);
    const int j = 8191 - (int)key;
    float xv = (x[(size_t)row * DIM + col] - stats[col]) * stats[64 + col];
    atomicAdd(&dw[(size_t)j * DIM + col], xv);
    if (col == 0) atomicAdd(&counts[j], 1.0f);
}

// ---------------- K5: epilogue ----------------
__global__ __launch_bounds__(256) void k_final(
    const float* __restrict__ emb, const float* __restrict__ cs,
    const float* __restrict__ dw, const float* __restrict__ counts,
    const float* __restrict__ stats, float* __restrict__ out)
{
    const int t = blockIdx.x * 256 + threadIdx.x; // over K*D
    const int k = t >> 6, d = t & 63;
    float csk = cs[k];
    float ns = csk * DECAYF + (1.f - DECAYF) * counts[k];
    float ne = (csk * emb[t] * DECAYF + (1.f - DECAYF) * dw[t]) / ns;
    out[KD + t] = ne;
    out[t] = ne * stats[128 + d] + stats[d];
    if (d == 0) out[2 * KD + k] = ns;
}

extern "C" void kernel_launch(void* const* d_in, const int* in_sizes, int n_in,
                              void* d_out, int out_size, void* d_ws, size_t ws_size,
                              hipStream_t stream)
{
    const float* x   = (const float*)d_in[0];
    const float* emb = (const float*)d_in[1];
    const float* cs  = (const float*)d_in[2];
    float* out = (float*)d_out;
    float* ws  = (float*)d_ws;

    float* stats  = ws + WS_STATS;
    float* nhckP  = ws + WS_NHCKP;
    half8* ebuf   = (half8*)(ws + WS_EBUF);
    float* psum   = ws + WS_PSUM;
    float* psq    = ws + WS_PSQ;
    unsigned* packed = (unsigned*)(ws + WS_PACKED);
    float* dw     = ws + WS_DW;
    float* counts = ws + WS_COUNTS;

    k_prep_stats<<<1024, 256, 0, stream>>>(emb, x, ebuf, nhckP, psum, psq,
                                           (float4*)(ws + WS_PACKED));
    k_colstats_final<<<1, 256, 0, stream>>>(psum, psq, stats);
    dim3 g3(NROWS / 256, KSPLIT);
    k_argmin32<<<g3, 256, 0, stream>>>(x, ebuf, nhckP, stats, packed);
    k_scatter<<<(NROWS * DIM) / 256, 256, 0, stream>>>(x, stats, packed, dw, counts);
    k_final<<<KD / 256, 256, 0, stream>>>(emb, cs, dw, counts, stats, out);
}